// Round 9
// baseline (357.189 us; speedup 1.0000x reference)
//
#include <hip/hip_runtime.h>
#include <hip/hip_fp16.h>
#include <math.h>

#define LOG2E 1.4426950408889634f
#define LN2F  0.6931471805599453f

constexpr int M   = 2048;
constexpr int N   = 2048;
constexpr int D   = 256;
constexpr int K   = 2048;   // reduce length (both directions)
constexpr int MP1 = 2049;   // M+1 == N+1
constexpr int UVS = 2052;   // padded u/v batch stride -> float4-aligned rows
constexpr int PPB = 1025;   // pairs per batch (512*2 rows + dustbin... = 1025 pairs of 2 outputs, last is single dustbin)

struct alignas(16) half8 { __half2 h[4]; };

__device__ inline half8 pack_half8(const float4& a, const float4& b) {
    half8 r;
    r.h[0] = __floats2half2_rn(a.x, a.y);
    r.h[1] = __floats2half2_rn(a.z, a.w);
    r.h[2] = __floats2half2_rn(b.x, b.y);
    r.h[3] = __floats2half2_rn(b.z, b.w);
    return r;
}

__device__ inline float fast_exp2(float x) {
#if __has_builtin(__builtin_amdgcn_exp2f)
    return __builtin_amdgcn_exp2f(x);
#else
    return exp2f(x);
#endif
}
__device__ inline float fast_log2(float x) {
#if __has_builtin(__builtin_amdgcn_logf)
    return __builtin_amdgcn_logf(x);   // v_log_f32 is log2
#else
    return log2f(x);
#endif
}
// NaN-guarded exp2 for identity (-inf) merges
__device__ inline float exp2g(float x) { return fast_exp2(fmaxf(x, -20000.0f)); }

__device__ inline void insert5(float t[5], float y) {
    float v = y, mx;
    #pragma unroll
    for (int k = 0; k < 5; ++k) { mx = fmaxf(t[k], v); v = fminf(t[k], v); t[k] = mx; }
}

__device__ inline void ce_desc(float& a, float& b) {
    float hi = fmaxf(a, b), lo = fminf(a, b); a = hi; b = lo;
}
// 19-CE sorting network for 8 elements, descending (y[0] = max).
__device__ inline void sort8_desc(float y[8]) {
    ce_desc(y[0],y[1]); ce_desc(y[2],y[3]); ce_desc(y[4],y[5]); ce_desc(y[6],y[7]);
    ce_desc(y[0],y[2]); ce_desc(y[1],y[3]); ce_desc(y[4],y[6]); ce_desc(y[5],y[7]);
    ce_desc(y[1],y[2]); ce_desc(y[5],y[6]); ce_desc(y[0],y[4]); ce_desc(y[3],y[7]);
    ce_desc(y[1],y[5]); ce_desc(y[2],y[6]);
    ce_desc(y[1],y[4]); ce_desc(y[3],y[6]);
    ce_desc(y[2],y[4]); ce_desc(y[3],y[5]);
    ce_desc(y[3],y[4]);
}

// top5-only merge: no lse state, no exp2 -- pure min/max network
__device__ inline void merge5t(float a[5], const float b[5]) {
    float r0 = fmaxf(a[0], b[0]);
    float r1 = fmaxf(fmaxf(a[1], b[1]), fminf(a[0], b[0]));
    float r2 = fmaxf(fmaxf(a[2], b[2]), fmaxf(fminf(a[1], b[0]), fminf(a[0], b[1])));
    float r3 = fmaxf(fmaxf(a[3], b[3]),
               fmaxf(fmaxf(fminf(a[2], b[0]), fminf(a[1], b[1])), fminf(a[0], b[2])));
    float r4 = fmaxf(fmaxf(a[4], b[4]),
               fmaxf(fmaxf(fminf(a[3], b[0]), fminf(a[2], b[1])),
                     fmaxf(fminf(a[1], b[2]), fminf(a[0], b[3]))));
    a[0] = r0; a[1] = r1; a[2] = r2; a[3] = r3; a[4] = r4;
}

__device__ inline void merge5t_shfl_xor(float t[5], int off) {
    float b[5];
    #pragma unroll
    for (int k = 0; k < 5; ++k) b[k] = __shfl_xor(t[k], off, 64);
    merge5t(t, b);
}

// dual top5-only butterfly level
__device__ inline void merge5t_shfl_xor2(float tA[5], float tB[5], int off) {
    float bA[5], bB[5];
    #pragma unroll
    for (int k = 0; k < 5; ++k) { bA[k] = __shfl_xor(tA[k], off, 64); bB[k] = __shfl_xor(tB[k], off, 64); }
    merge5t(tA, bA);
    merge5t(tB, bB);
}

__device__ inline void online_add(float t[5], float& s, float y) {
    float m_old = t[0];
    float m_new = fmaxf(m_old, y);
    s = s * exp2g(m_old - m_new) + fast_exp2(y - m_new);
    insert5(t, y);
}

// sort group of 8, record per-group (max, sum-at-max), fold top5 only
__device__ inline void group_accum_t(bool first, float t[5], float z[8],
                                     float& mgv, float& sgv) {
    sort8_desc(z);
    float gs = 1.0f;
    #pragma unroll
    for (int k = 1; k < 8; ++k) gs += fast_exp2(z[k] - z[0]);
    mgv = z[0]; sgv = gs;
    if (first) { t[0]=z[0]; t[1]=z[1]; t[2]=z[2]; t[3]=z[3]; t[4]=z[4]; }
    else merge5t(t, z);
}

__device__ inline float gelu_exact(float x) {
    return 0.5f * x * (1.0f + erff(x * 0.70710678118654752f));
}

__device__ inline float wave_sum(float x) {
    #pragma unroll
    for (int off = 32; off >= 1; off >>= 1) x += __shfl_xor(x, off, 64);
    return x;
}
__device__ inline void wave_sum2(float& x, float& y) {
    #pragma unroll
    for (int off = 32; off >= 1; off >>= 1) {
        float xs = __shfl_xor(x, off, 64);
        float ys = __shfl_xor(y, off, 64);
        x += xs; y += ys;
    }
}
__device__ inline void wave_sum4(float& a, float& b, float& c, float& d) {
    #pragma unroll
    for (int off = 32; off >= 1; off >>= 1) {
        float as = __shfl_xor(a, off, 64);
        float bs = __shfl_xor(b, off, 64);
        float cs = __shfl_xor(c, off, 64);
        float ds = __shfl_xor(d, off, 64);
        a += as; b += bs; c += cs; d += ds;
    }
}

// one-wave MLP, fused-moment LN (single wave_sum2 of (sum, sumsq) per LN).
__device__ inline float mlp_wave_fast(const float f[16], int j,
    const float* __restrict__ w1, const float* __restrict__ b1,
    const float* __restrict__ g1, const float* __restrict__ be1,
    const float* __restrict__ w2, const float* __restrict__ b2,
    const float* __restrict__ g2, const float* __restrict__ be2,
    const float* __restrict__ w3, const float* __restrict__ b3)
{
    float h = b1[j];
    #pragma unroll
    for (int k = 0; k < 16; ++k) h = fmaf(f[k], w1[j * 16 + k], h);
    h = gelu_exact(h);
    float sm = h, sq = h * h;
    wave_sum2(sm, sq);
    float mu  = sm * (1.0f / 64.0f);
    float var = sq * (1.0f / 64.0f) - mu * mu;
    float hn  = (h - mu) * rsqrtf(var + 1e-5f) * g1[j] + be1[j];

    float a0 = b2[j], a1 = 0.0f;
    #pragma unroll
    for (int k = 0; k < 64; k += 2) {
        a0 = fmaf(__shfl(hn, k, 64),     w2[j * 64 + k],     a0);
        a1 = fmaf(__shfl(hn, k + 1, 64), w2[j * 64 + k + 1], a1);
    }
    float h2 = gelu_exact(a0 + a1);
    sm = h2; sq = h2 * h2;
    wave_sum2(sm, sq);
    mu  = sm * (1.0f / 64.0f);
    var = sq * (1.0f / 64.0f) - mu * mu;
    float hn2 = (h2 - mu) * rsqrtf(var + 1e-5f) * g2[j] + be2[j];
    return wave_sum(hn2 * w3[j]) + b3[0];
}

// dual MLP, fused-moment LN via wave_sum4 (both rows' (sum,sumsq) in one butterfly)
__device__ inline void mlp_wave2_fast(const float fA[16], const float fB[16], int j,
    const float* __restrict__ w1, const float* __restrict__ b1,
    const float* __restrict__ g1, const float* __restrict__ be1,
    const float* __restrict__ w2, const float* __restrict__ b2,
    const float* __restrict__ g2, const float* __restrict__ be2,
    const float* __restrict__ w3, const float* __restrict__ b3,
    float& oA, float& oB)
{
    float hA = b1[j], hB = hA;
    #pragma unroll
    for (int k = 0; k < 16; ++k) {
        float w = w1[j * 16 + k];
        hA = fmaf(fA[k], w, hA);
        hB = fmaf(fB[k], w, hB);
    }
    hA = gelu_exact(hA); hB = gelu_exact(hB);
    float smA = hA, sqA = hA * hA, smB = hB, sqB = hB * hB;
    wave_sum4(smA, sqA, smB, sqB);
    float muA = smA * (1.0f / 64.0f), muB = smB * (1.0f / 64.0f);
    float vA  = sqA * (1.0f / 64.0f) - muA * muA;
    float vB  = sqB * (1.0f / 64.0f) - muB * muB;
    float hnA = (hA - muA) * rsqrtf(vA + 1e-5f) * g1[j] + be1[j];
    float hnB = (hB - muB) * rsqrtf(vB + 1e-5f) * g1[j] + be1[j];

    float a0A = b2[j], a1A = 0.0f, a0B = b2[j], a1B = 0.0f;
    #pragma unroll
    for (int k = 0; k < 64; k += 2) {
        float w0 = w2[j * 64 + k], w1v = w2[j * 64 + k + 1];
        float sA0 = __shfl(hnA, k, 64),     sB0 = __shfl(hnB, k, 64);
        float sA1 = __shfl(hnA, k + 1, 64), sB1 = __shfl(hnB, k + 1, 64);
        a0A = fmaf(sA0, w0, a0A); a0B = fmaf(sB0, w0, a0B);
        a1A = fmaf(sA1, w1v, a1A); a1B = fmaf(sB1, w1v, a1B);
    }
    float h2A = gelu_exact(a0A + a1A), h2B = gelu_exact(a0B + a1B);
    smA = h2A; sqA = h2A * h2A; smB = h2B; sqB = h2B * h2B;
    wave_sum4(smA, sqA, smB, sqB);
    muA = smA * (1.0f / 64.0f); muB = smB * (1.0f / 64.0f);
    vA  = sqA * (1.0f / 64.0f) - muA * muA;
    vB  = sqB * (1.0f / 64.0f) - muB * muB;
    float hn2A = (h2A - muA) * rsqrtf(vA + 1e-5f) * g2[j] + be2[j];
    float hn2B = (h2B - muB) * rsqrtf(vB + 1e-5f) * g2[j] + be2[j];
    float zA = hn2A * w3[j], zB = hn2B * w3[j];
    wave_sum2(zA, zB);
    oA = zA + b3[0];
    oB = zB + b3[0];
}

__device__ inline void feats_from(const float t[5], float s, float l2w,
                                  const float* __restrict__ dd, float f[16], float& un)
{
    float lse = t[0] + fast_log2(s);
    un = l2w - lse;
    f[0] = l2w * LN2F;
    f[1] = un  * LN2F;
    f[2] = 0.0f;
    f[3] = (t[0] - t[1]) * LN2F;
    f[4] = (t[0] - t[2]) * LN2F;
    f[5] = (t[0] - t[3]) * LN2F;
    f[6] = (t[0] - t[4]) * LN2F;
    f[7] = (lse - t[0]) * LN2F;
    #pragma unroll
    for (int p = 0; p < 8; ++p) f[8 + p] = dd[p];
}

// ---------------------------------------------------------------------------
// proj, K-split: grid (9, B, 16) [z = which*8 + ks], block 256. (unchanged)
// ---------------------------------------------------------------------------
__global__ __launch_bounds__(256) void proj_part(
    const float* __restrict__ mdesc0, const float* __restrict__ mdesc1,
    const float* __restrict__ pA_w, const float* __restrict__ pB_w,
    float* __restrict__ ppart, int B)
{
    const int which = blockIdx.z >> 3;
    const int ks    = blockIdx.z & 7;
    const float* mdesc = which ? mdesc1 : mdesc0;
    const float* pw    = which ? pB_w : pA_w;

    __shared__ float swT[32 * 8];   // swT[d0*8+p]
    const int tid = threadIdx.x;
    {
        int p = tid >> 5, d0 = tid & 31;
        swT[d0 * 8 + p] = pw[p * D + ks * 32 + d0];
    }
    __syncthreads();

    const int m = blockIdx.x * 256 + tid;
    const int b = blockIdx.y;
    if (m >= M) return;

    float acc[8];
    #pragma unroll
    for (int p = 0; p < 8; ++p) acc[p] = 0.0f;
    const float* base = mdesc + ((size_t)b * D + ks * 32) * M + m;
    #pragma unroll 4
    for (int d0 = 0; d0 < 32; ++d0) {
        float x = base[(size_t)d0 * M];
        #pragma unroll
        for (int p = 0; p < 8; ++p) acc[p] = fmaf(x, swT[d0 * 8 + p], acc[p]);
    }
    float4* o = (float4*)(ppart + (((size_t)(which * B + b)) * MP1 + m) * 64 + ks * 8);
    o[0] = make_float4(acc[0], acc[1], acc[2], acc[3]);
    o[1] = make_float4(acc[4], acc[5], acc[6], acc[7]);
}

// grid (9, B, 2), block 256: sum 8 K-partials + bias; dustbin row m==M -> 0
__global__ __launch_bounds__(256) void proj_combine(
    const float* __restrict__ ppart,
    const float* __restrict__ pA_b, const float* __restrict__ pB_b,
    float* __restrict__ dA, float* __restrict__ dB, int B)
{
    const int which = blockIdx.z;
    const float* pb = which ? pB_b : pA_b;
    float* dOut     = which ? dB   : dA;
    const int m = blockIdx.x * 256 + threadIdx.x;
    const int b = blockIdx.y;
    if (m > M) return;
    float* out = dOut + ((size_t)b * MP1 + m) * 8;
    if (m == M) {
        #pragma unroll
        for (int p = 0; p < 8; ++p) out[p] = 0.0f;
        return;
    }
    float acc[8];
    #pragma unroll
    for (int p = 0; p < 8; ++p) acc[p] = pb[p];
    const float4* pp = (const float4*)(ppart + (((size_t)(which * B + b)) * MP1 + m) * 64);
    #pragma unroll
    for (int ks = 0; ks < 8; ++ks) {
        float4 x0 = pp[2 * ks], x1 = pp[2 * ks + 1];
        acc[0] += x0.x; acc[1] += x0.y; acc[2] += x0.z; acc[3] += x0.w;
        acc[4] += x1.x; acc[5] += x1.y; acc[6] += x1.z; acc[7] += x1.w;
    }
    #pragma unroll
    for (int p = 0; p < 8; ++p) out[p] = acc[p];
}

// ---------------------------------------------------------------------------
// row0 helpers: load one pair of fp32 rows into regs; compute+store.
// ---------------------------------------------------------------------------
__device__ inline void row0_load_pair(const float* __restrict__ scores,
                                      int b, int io, int lane,
                                      float4 qa[8], float4 qb[8])
{
    if (io < M) {
        const float4* sA4 = (const float4*)(scores + ((size_t)b * M + io) * N);
        const float4* sB4 = sA4 + (N / 4);
        #pragma unroll
        for (int j = 0; j < 4; ++j) {
            qa[2 * j]     = sA4[2 * lane + 128 * j];
            qa[2 * j + 1] = sA4[2 * lane + 128 * j + 1];
            qb[2 * j]     = sB4[2 * lane + 128 * j];
            qb[2 * j + 1] = sB4[2 * lane + 128 * j + 1];
        }
    }
}

__device__ inline void row0_compute_store(
    int b, int io, int lane,
    const float4 qa[8], const float4 qb[8],
    __half* __restrict__ sh, float alpha2,
    const float* __restrict__ dA, float* __restrict__ u,
    const float* __restrict__ w1, const float* __restrict__ b1,
    const float* __restrict__ g1, const float* __restrict__ be1,
    const float* __restrict__ w2, const float* __restrict__ b2,
    const float* __restrict__ g2, const float* __restrict__ be2,
    const float* __restrict__ w3, const float* __restrict__ b3)
{
    if (io < M) {
        half8* hA8 = (half8*)(sh + ((size_t)b * M + io) * N);
        half8* hB8 = hA8 + (N / 8);
        float tA[5], tB[5];
        float mgA[4], sgA[4], mgB[4], sgB[4];
        #pragma unroll
        for (int j = 0; j < 4; ++j) {
            float4 qa0 = qa[2 * j], qa1 = qa[2 * j + 1];
            float4 qb0 = qb[2 * j], qb1 = qb[2 * j + 1];
            hA8[64 * j + lane] = pack_half8(qa0, qa1);
            hB8[64 * j + lane] = pack_half8(qb0, qb1);
            float zA[8] = {qa0.x*LOG2E, qa0.y*LOG2E, qa0.z*LOG2E, qa0.w*LOG2E,
                           qa1.x*LOG2E, qa1.y*LOG2E, qa1.z*LOG2E, qa1.w*LOG2E};
            float zB[8] = {qb0.x*LOG2E, qb0.y*LOG2E, qb0.z*LOG2E, qb0.w*LOG2E,
                           qb1.x*LOG2E, qb1.y*LOG2E, qb1.z*LOG2E, qb1.w*LOG2E};
            group_accum_t(j == 0, tA, zA, mgA[j], sgA[j]);
            group_accum_t(j == 0, tB, zB, mgB[j], sgB[j]);
        }

        #pragma unroll
        for (int off = 32; off >= 1; off >>= 1) merge5t_shfl_xor2(tA, tB, off);

        float mA = tA[0], mB = tB[0];
        float slA = 0.0f, slB = 0.0f;
        #pragma unroll
        for (int j = 0; j < 4; ++j) {
            slA = fmaf(sgA[j], exp2g(mgA[j] - mA), slA);
            slB = fmaf(sgB[j], exp2g(mgB[j] - mB), slB);
        }
        wave_sum2(slA, slB);
        float sA = slA, sB = slB;

        online_add(tA, sA, alpha2);
        online_add(tB, sB, alpha2);

        float fA[16], fB[16], unA, unB;
        const float* ddA = dA + (size_t)(b * MP1 + io) * 8;
        feats_from(tA, sA, -12.0f, ddA, fA, unA);
        feats_from(tB, sB, -12.0f, ddA + 8, fB, unB);

        float oA, oB;
        mlp_wave2_fast(fA, fB, lane, w1, b1, g1, be1, w2, b2, g2, be2, w3, b3, oA, oB);
        if (lane == 0) {
            u[(size_t)b * UVS + io]     = unA + oA * LOG2E;
            u[(size_t)b * UVS + io + 1] = unB + oB * LOG2E;
        }
    } else {
        // dustbin row io == M: all elements alpha2 (v == 0 at iter 0)
        float t[5] = {alpha2, alpha2, alpha2, alpha2, alpha2};
        float s = 2049.0f;
        float f[16], un;
        const float* dd = dA + (size_t)(b * MP1 + M) * 8;
        feats_from(t, s, -1.0f, dd, f, un);
        float o = mlp_wave_fast(f, lane, w1, b1, g1, be1, w2, b2, g2, be2, w3, b3);
        if (lane == 0) u[(size_t)b * UVS + M] = un + o * LOG2E;
    }
}

// ---------------------------------------------------------------------------
// Iter-0 row pass, persistent: grid (512) x 256 = 2048 waves; each wave
// grid-strides over pairs with register double-buffer prefetch, so next
// pair's loads are in flight during current pair's compute.
// ---------------------------------------------------------------------------
__global__ __launch_bounds__(256, 2) void row0_fused(
    const float* __restrict__ scores, __half* __restrict__ sh,
    const float* __restrict__ alpha, const float* __restrict__ dA,
    float* __restrict__ u, int total_pairs,
    const float* __restrict__ w1, const float* __restrict__ b1,
    const float* __restrict__ g1, const float* __restrict__ be1,
    const float* __restrict__ w2, const float* __restrict__ b2,
    const float* __restrict__ g2, const float* __restrict__ be2,
    const float* __restrict__ w3, const float* __restrict__ b3)
{
    const int lane = threadIdx.x & 63;
    const int wid  = blockIdx.x * 4 + (threadIdx.x >> 6);
    const int NW   = gridDim.x * 4;
    const float alpha2 = alpha[0] * LOG2E;

    int p = wid;
    if (p >= total_pairs) return;
    int b = p / PPB, io = (p - b * PPB) * 2;

    float4 qa[8], qb[8];
    row0_load_pair(scores, b, io, lane, qa, qb);

    while (true) {
        int pn = p + NW;
        bool more = pn < total_pairs;
        int bn = 0, ion = 0;
        float4 nqa[8], nqb[8];
        if (more) {
            bn = pn / PPB; ion = (pn - bn * PPB) * 2;
            row0_load_pair(scores, bn, ion, lane, nqa, nqb);
        }
        row0_compute_store(b, io, lane, qa, qb, sh, alpha2, dA, u,
                           w1, b1, g1, be1, w2, b2, g2, be2, w3, b3);
        if (!more) break;
        p = pn; b = bn; io = ion;
        #pragma unroll
        for (int j = 0; j < 8; ++j) { qa[j] = nqa[j]; qb[j] = nqb[j]; }
    }
}

// ---------------------------------------------------------------------------
// fp16 transpose: sh[b][r][c] -> shT[b][c][r]. 64x64 LDS tiles. (unchanged)
// ---------------------------------------------------------------------------
__global__ __launch_bounds__(256) void transpose_half(
    const __half* __restrict__ sh, __half* __restrict__ shT)
{
    __shared__ unsigned short a[64][65];
    const int b  = blockIdx.z;
    const int r0 = blockIdx.x * 64;
    const int c0 = blockIdx.y * 64;
    const int t  = threadIdx.x;

    const __half* src = sh + ((size_t)b * M + r0) * N + c0;
    #pragma unroll
    for (int i = 0; i < 2; ++i) {
        int s = t + 256 * i;            // 512 half8 slots
        int r = s >> 3, c8 = (s & 7) * 8;
        half8 hv = *(const half8*)(src + (size_t)r * N + c8);
        const unsigned short* pv = (const unsigned short*)&hv;
        #pragma unroll
        for (int k = 0; k < 8; ++k) a[r][c8 + k] = pv[k];
    }
    __syncthreads();
    __half* dst = shT + ((size_t)b * N + c0) * M + r0;
    #pragma unroll
    for (int i = 0; i < 2; ++i) {
        int s = t + 256 * i;
        int c = s >> 3, r8 = (s & 7) * 8;
        half8 ov;
        unsigned short* po = (unsigned short*)&ov;
        #pragma unroll
        for (int k = 0; k < 8; ++k) po[k] = a[r8 + k][c];
        *(half8*)(dst + (size_t)c * M + r8) = ov;
    }
}

// ---------------------------------------------------------------------------
// rc helpers: load one pair (2 fp16 rows + vk slice) into regs; compute+store.
// ---------------------------------------------------------------------------
__device__ inline void rc_load_pair(const __half* __restrict__ mat,
                                    const float* __restrict__ vk_base,
                                    int b, int io, int lane,
                                    half8 ha[4], half8 hb[4], float4 vv[8])
{
    const float4* vk4 = (const float4*)(vk_base + (size_t)b * UVS);
    #pragma unroll
    for (int j = 0; j < 4; ++j) {
        vv[2 * j]     = vk4[2 * lane + 128 * j];
        vv[2 * j + 1] = vk4[2 * lane + 128 * j + 1];
    }
    if (io < M) {
        const half8* hA8 = (const half8*)(mat + ((size_t)b * M + io) * K);
        const half8* hB8 = hA8 + (K / 8);
        #pragma unroll
        for (int j = 0; j < 4; ++j) { ha[j] = hA8[64 * j + lane]; hb[j] = hB8[64 * j + lane]; }
    }
}

__device__ inline void rc_compute_store(
    int b, int io, int lane,
    const half8 ha[4], const half8 hb[4], const float4 vv[8],
    float alpha2, const float* __restrict__ vk_base,
    const float* __restrict__ desc, float* __restrict__ out,
    const float* __restrict__ w1, const float* __restrict__ b1,
    const float* __restrict__ g1, const float* __restrict__ be1,
    const float* __restrict__ w2, const float* __restrict__ b2,
    const float* __restrict__ g2, const float* __restrict__ be2,
    const float* __restrict__ w3, const float* __restrict__ b3)
{
    const float vkK = vk_base[(size_t)b * UVS + K];
    if (io < M) {
        float tA[5], tB[5];
        float mgA[4], sgA[4], mgB[4], sgB[4];
        #pragma unroll
        for (int j = 0; j < 4; ++j) {
            float2 a0 = __half22float2(ha[j].h[0]), a1 = __half22float2(ha[j].h[1]);
            float2 a2 = __half22float2(ha[j].h[2]), a3 = __half22float2(ha[j].h[3]);
            float2 b0 = __half22float2(hb[j].h[0]), b1v = __half22float2(hb[j].h[1]);
            float2 b2v = __half22float2(hb[j].h[2]), b3v = __half22float2(hb[j].h[3]);
            float4 w0 = vv[2 * j], w1v = vv[2 * j + 1];
            float zA[8] = {fmaf(a0.x,LOG2E,w0.x),  fmaf(a0.y,LOG2E,w0.y),
                           fmaf(a1.x,LOG2E,w0.z),  fmaf(a1.y,LOG2E,w0.w),
                           fmaf(a2.x,LOG2E,w1v.x), fmaf(a2.y,LOG2E,w1v.y),
                           fmaf(a3.x,LOG2E,w1v.z), fmaf(a3.y,LOG2E,w1v.w)};
            float zB[8] = {fmaf(b0.x,LOG2E,w0.x),  fmaf(b0.y,LOG2E,w0.y),
                           fmaf(b1v.x,LOG2E,w0.z), fmaf(b1v.y,LOG2E,w0.w),
                           fmaf(b2v.x,LOG2E,w1v.x), fmaf(b2v.y,LOG2E,w1v.y),
                           fmaf(b3v.x,LOG2E,w1v.z), fmaf(b3v.y,LOG2E,w1v.w)};
            group_accum_t(j == 0, tA, zA, mgA[j], sgA[j]);
            group_accum_t(j == 0, tB, zB, mgB[j], sgB[j]);
        }

        #pragma unroll
        for (int off = 32; off >= 1; off >>= 1) merge5t_shfl_xor2(tA, tB, off);

        float mA = tA[0], mB = tB[0];
        float slA = 0.0f, slB = 0.0f;
        #pragma unroll
        for (int j = 0; j < 4; ++j) {
            slA = fmaf(sgA[j], exp2g(mgA[j] - mA), slA);
            slB = fmaf(sgB[j], exp2g(mgB[j] - mB), slB);
        }
        wave_sum2(slA, slB);
        float sA = slA, sB = slB;

        float extra = alpha2 + vkK;
        online_add(tA, sA, extra);
        online_add(tB, sB, extra);

        float fA[16], fB[16], unA, unB;
        const float* ddA = desc + (size_t)(b * MP1 + io) * 8;
        feats_from(tA, sA, -12.0f, ddA, fA, unA);
        feats_from(tB, sB, -12.0f, ddA + 8, fB, unB);

        float oA, oB;
        mlp_wave2_fast(fA, fB, lane, w1, b1, g1, be1, w2, b2, g2, be2, w3, b3, oA, oB);
        if (lane == 0) {
            out[(size_t)b * UVS + io]     = unA + oA * LOG2E;
            out[(size_t)b * UVS + io + 1] = unB + oB * LOG2E;
        }
    } else {
        // dustbin output io == M: z[k] = alpha2 + vk[k] (vv layout; order-invariant)
        float t[5];
        float mg[4], sg[4];
        #pragma unroll
        for (int j = 0; j < 4; ++j) {
            float4 w0 = vv[2 * j], w1v = vv[2 * j + 1];
            float z[8] = {alpha2+w0.x,  alpha2+w0.y,  alpha2+w0.z,  alpha2+w0.w,
                          alpha2+w1v.x, alpha2+w1v.y, alpha2+w1v.z, alpha2+w1v.w};
            group_accum_t(j == 0, t, z, mg[j], sg[j]);
        }
        #pragma unroll
        for (int off = 32; off >= 1; off >>= 1) merge5t_shfl_xor(t, off);
        float m = t[0];
        float sl = 0.0f;
        #pragma unroll
        for (int j = 0; j < 4; ++j) sl = fmaf(sg[j], exp2g(mg[j] - m), sl);
        float s = wave_sum(sl);
        online_add(t, s, alpha2 + vkK);

        float f[16], un;
        const float* dd = desc + (size_t)(b * MP1 + M) * 8;
        feats_from(t, s, -1.0f, dd, f, un);
        float o = mlp_wave_fast(f, lane, w1, b1, g1, be1, w2, b2, g2, be2, w3, b3);
        if (lane == 0) out[(size_t)b * UVS + M] = un + o * LOG2E;
    }
}

// ---------------------------------------------------------------------------
// Generic fp16 reduce + fused MLP pass, persistent: grid (512) x 256 =
// 2048 waves; grid-stride over pairs with register double-buffer prefetch.
// ---------------------------------------------------------------------------
__global__ __launch_bounds__(256, 2) void rc_fused(
    const __half* __restrict__ mat, const float* __restrict__ vk_base,
    const float* __restrict__ desc, const float* __restrict__ alpha,
    float* __restrict__ out, int total_pairs,
    const float* __restrict__ w1, const float* __restrict__ b1,
    const float* __restrict__ g1, const float* __restrict__ be1,
    const float* __restrict__ w2, const float* __restrict__ b2,
    const float* __restrict__ g2, const float* __restrict__ be2,
    const float* __restrict__ w3, const float* __restrict__ b3)
{
    const int lane = threadIdx.x & 63;
    const int wid  = blockIdx.x * 4 + (threadIdx.x >> 6);
    const int NW   = gridDim.x * 4;
    const float alpha2 = alpha[0] * LOG2E;

    int p = wid;
    if (p >= total_pairs) return;
    int b = p / PPB, io = (p - b * PPB) * 2;

    half8 ha[4], hb[4]; float4 vv[8];
    rc_load_pair(mat, vk_base, b, io, lane, ha, hb, vv);

    while (true) {
        int pn = p + NW;
        bool more = pn < total_pairs;
        int bn = 0, ion = 0;
        half8 nha[4], nhb[4]; float4 nvv[8];
        if (more) {
            bn = pn / PPB; ion = (pn - bn * PPB) * 2;
            rc_load_pair(mat, vk_base, bn, ion, lane, nha, nhb, nvv);
        }
        rc_compute_store(b, io, lane, ha, hb, vv, alpha2, vk_base, desc, out,
                         w1, b1, g1, be1, w2, b2, g2, be2, w3, b3);
        if (!more) break;
        p = pn; b = bn; io = ion;
        #pragma unroll
        for (int j = 0; j < 4; ++j) { ha[j] = nha[j]; hb[j] = nhb[j]; }
        #pragma unroll
        for (int j = 0; j < 8; ++j) vv[j] = nvv[j];
    }
}

// ---------------------------------------------------------------------------
// out[b,r,c] = S*LOG2E + u[b,r] + v[b,c] + 12.  grid (2049, B), block 256.
// (unchanged)
// ---------------------------------------------------------------------------
__global__ __launch_bounds__(256) void final_kernel(
    const __half* __restrict__ sh, const float* __restrict__ alpha,
    const float* __restrict__ u, const float* __restrict__ v,
    float* __restrict__ out)
{
    const int r = blockIdx.x;
    const int b = blockIdx.y;
    const int tid = threadIdx.x;
    const float alpha2 = alpha[0] * LOG2E;
    const float* vb = v + (size_t)b * UVS;
    const float4* v4 = (const float4*)vb;
    const float ur = u[(size_t)b * UVS + r] + 12.0f;
    float* orow = out + ((size_t)b * MP1 + r) * MP1;

    float4 w0 = v4[2 * tid], w1v = v4[2 * tid + 1];
    const int c = tid * 8;
    if (r < M) {
        half8 hv = *(const half8*)(sh + ((size_t)b * M + r) * N + c);
        float2 a0 = __half22float2(hv.h[0]), a1 = __half22float2(hv.h[1]);
        float2 a2 = __half22float2(hv.h[2]), a3 = __half22float2(hv.h[3]);
        orow[c]     = fmaf(a0.x, LOG2E, ur + w0.x);
        orow[c + 1] = fmaf(a0.y, LOG2E, ur + w0.y);
        orow[c + 2] = fmaf(a1.x, LOG2E, ur + w0.z);
        orow[c + 3] = fmaf(a1.y, LOG2E, ur + w0.w);
        orow[c + 4] = fmaf(a2.x, LOG2E, ur + w1v.x);
        orow[c + 5] = fmaf(a2.y, LOG2E, ur + w1v.y);
        orow[c + 6] = fmaf(a3.x, LOG2E, ur + w1v.z);
        orow[c + 7] = fmaf(a3.y, LOG2E, ur + w1v.w);
    } else {
        orow[c]     = alpha2 + ur + w0.x;
        orow[c + 1] = alpha2 + ur + w0.y;
        orow[c + 2] = alpha2 + ur + w0.z;
        orow[c + 3] = alpha2 + ur + w0.w;
        orow[c + 4] = alpha2 + ur + w1v.x;
        orow[c + 5] = alpha2 + ur + w1v.y;
        orow[c + 6] = alpha2 + ur + w1v.z;
        orow[c + 7] = alpha2 + ur + w1v.w;
    }
    if (tid == 0) orow[N] = alpha2 + ur + vb[N];
}

extern "C" void kernel_launch(void* const* d_in, const int* in_sizes, int n_in,
                              void* d_out, int out_size, void* d_ws, size_t ws_size,
                              hipStream_t stream) {
    const float* scores = (const float*)d_in[0];
    const float* alpha  = (const float*)d_in[1];
    const float* mdesc0 = (const float*)d_in[2];
    const float* mdesc1 = (const float*)d_in[3];
    const float* pA_w = (const float*)d_in[4];
    const float* pA_b = (const float*)d_in[5];
    const float* pB_w = (const float*)d_in[6];
    const float* pB_b = (const float*)d_in[7];
    const float* rW[10]; const float* cW[10];
    for (int k = 0; k < 10; ++k) rW[k] = (const float*)d_in[8 + k];
    for (int k = 0; k < 10; ++k) cW[k] = (const float*)d_in[18 + k];
    float* out = (float*)d_out;

    const int B = in_sizes[0] / (M * N);

    float* ws = (float*)d_ws;
    float* u     = ws;                              // B*UVS
    float* v     = u + (size_t)B * UVS;             // B*UVS
    float* dA    = v + (size_t)B * UVS;             // B*MP1*8
    float* dB    = dA + (size_t)B * MP1 * 8;        // B*MP1*8
    float* ppart = dB + (size_t)B * MP1 * 8;        // 2*B*MP1*64
    __half* sh   = (__half*)(ppart + (size_t)2 * B * MP1 * 64); // B*M*N halfs
    __half* shT  = sh + (size_t)B * M * N;                      // B*N*M halfs

    const int CB  = (MP1 + 255) / 256;   // 9
    const int RCB = 512;                 // persistent blocks (2048 waves)
    const int total_pairs = B * PPB;

    proj_part<<<dim3(CB, B, 16), 256, 0, stream>>>(
        mdesc0, mdesc1, pA_w, pB_w, ppart, B);
    proj_combine<<<dim3(CB, B, 2), 256, 0, stream>>>(
        ppart, pA_b, pB_b, dA, dB, B);

    // iter 0: row pass on fp32 (v == 0), produce sh; transpose; col pass
    row0_fused<<<dim3(RCB), 256, 0, stream>>>(
        scores, sh, alpha, dA, u, total_pairs,
        rW[0], rW[1], rW[2], rW[3], rW[4], rW[5], rW[6], rW[7], rW[8], rW[9]);
    transpose_half<<<dim3(32, 32, B), 256, 0, stream>>>(sh, shT);
    rc_fused<<<dim3(RCB), 256, 0, stream>>>(
        shT, u, dB, alpha, v, total_pairs,
        cW[0], cW[1], cW[2], cW[3], cW[4], cW[5], cW[6], cW[7], cW[8], cW[9]);

    for (int it = 1; it < 3; ++it) {
        rc_fused<<<dim3(RCB), 256, 0, stream>>>(
            sh, v, dA, alpha, u, total_pairs,
            rW[0], rW[1], rW[2], rW[3], rW[4], rW[5], rW[6], rW[7], rW[8], rW[9]);
        rc_fused<<<dim3(RCB), 256, 0, stream>>>(
            shT, u, dB, alpha, v, total_pairs,
            cW[0], cW[1], cW[2], cW[3], cW[4], cW[5], cW[6], cW[7], cW[8], cW[9]);
    }
    final_kernel<<<dim3(MP1, B), 256, 0, stream>>>(sh, alpha, u, v, out);
}